// Round 4
// baseline (249.336 us; speedup 1.0000x reference)
//
#include <hip/hip_runtime.h>
#include <math.h>

// Problem constants: cost [8,1,48,128,240] f32, spg [8,9,512,960] f32
#define BB 8
#define DD 48
#define HH 128
#define WW 240
#define HW (HH * WW)
#define FH (4 * HH)   // 512
#define FW (4 * WW)   // 960
#define FHW (FH * FW)

// Fused tiling: each block owns a 60x8 coarse tile (=> 240x32 fine tile).
// Grid = 4 x-tiles * 16 y-tiles * 8 batches = 512 blocks (2 blocks/CU).
#define TW 60
#define TH 8
#define HALO_W (TW + 2)          // 62
#define HALO_H (TH + 2)          // 10
#define NPX (HALO_W * HALO_H)    // 620
#define NQ  (TW * 4 * TH)        // 1920 fine x-quads per block

typedef float vf4 __attribute__((ext_vector_type(4)));

__global__ __launch_bounds__(256) void fused_disp_kernel(const float* __restrict__ cost,
                                                         const float* __restrict__ spg,
                                                         float* __restrict__ out) {
    __shared__ float ld[HALO_H][HALO_W];   // disp4 halo tile, 2.48 KB

    int tid = threadIdx.x;
    int blk = blockIdx.x;
    int bx = blk & 3;            // 4 tiles in x
    int by = (blk >> 2) & 15;    // 16 tiles in y
    int b  = blk >> 6;           // 8 batches
    int cw0 = bx * TW;
    int ch0 = by * TH;

    // ---------- Phase A: top-2 + softmax-of-2 disp4 over the halo tile ----------
    const float* cbase = cost + (size_t)b * DD * HW;
    float m1[3], m2[3], i1[3], i2[3];
    const float* addr[3];
    bool inb[3], valid[3];
    int hr_[3], hc_[3];
#pragma unroll
    for (int s = 0; s < 3; ++s) {
        int idx = tid + s * 256;
        valid[s] = idx < NPX;
        int hr = valid[s] ? (idx / HALO_W) : 0;
        int hc = valid[s] ? (idx - hr * HALO_W) : 0;
        hr_[s] = hr; hc_[s] = hc;
        int cy = ch0 + hr - 1;
        int cx = cw0 + hc - 1;
        inb[s] = valid[s] & (cy >= 0) & (cy < HH) & (cx >= 0) & (cx < WW);
        addr[s] = inb[s] ? (cbase + (size_t)cy * WW + cx) : cbase;
        m1[s] = -INFINITY; m2[s] = -INFINITY; i1[s] = 0.f; i2[s] = 0.f;
    }
#pragma unroll
    for (int dd = 0; dd < DD; dd += 4) {
        float v[4][3];
#pragma unroll
        for (int u = 0; u < 4; ++u)
#pragma unroll
            for (int s = 0; s < 3; ++s)
                v[u][s] = addr[s][(size_t)(dd + u) * HW];
#pragma unroll
        for (int u = 0; u < 4; ++u) {
            float fd = (float)(dd + u);
#pragma unroll
            for (int s = 0; s < 3; ++s) {
                float vv = v[u][s];
                // strict > keeps lower index on ties (matches jax.lax.top_k)
                bool g1 = vv > m1[s];
                bool g2 = vv > m2[s];
                m2[s] = g1 ? m1[s] : (g2 ? vv : m2[s]);
                i2[s] = g1 ? i1[s] : (g2 ? fd : i2[s]);
                m1[s] = g1 ? vv : m1[s];
                i1[s] = g1 ? fd : i1[s];
            }
        }
    }
#pragma unroll
    for (int s = 0; s < 3; ++s) {
        if (valid[s]) {
            float e = __expf(m2[s] - m1[s]);     // e <= 1 since m1 >= m2
            float sg = e / (1.f + e);
            float dv = i1[s] + (i2[s] - i1[s]) * sg;
            ld[hr_[s]][hc_[s]] = inb[s] ? dv : 0.f;   // zero-pad outside image
        }
    }
    __syncthreads();

    // ---------- Phase B: spg softmax * 3x3 patch, 4x nearest upsample ----------
    // One iteration handles 4 consecutive fine x (same coarse pixel).
    for (int q = tid; q < NQ; q += 256) {
        int qx = q % TW;             // coarse x within tile
        int qy = q / TW;             // fine y within tile (0..31)
        int y  = 4 * ch0 + qy;
        int hr = (qy >> 2);          // coarse y within tile

        float p[9];
#pragma unroll
        for (int i = 0; i < 3; ++i)
#pragma unroll
            for (int j = 0; j < 3; ++j)
                p[i * 3 + j] = ld[hr + i][qx + j];

        const float* sp = spg + ((size_t)b * 9 * FH + y) * FW + (size_t)(cw0 + qx) * 4;
        float s[9][4];
#pragma unroll
        for (int c = 0; c < 9; ++c) {
            vf4 v = __builtin_nontemporal_load(
                reinterpret_cast<const vf4*>(sp + (size_t)c * FHW));
            s[c][0] = v.x; s[c][1] = v.y; s[c][2] = v.z; s[c][3] = v.w;
        }

        vf4 ov;
#pragma unroll
        for (int k = 0; k < 4; ++k) {
            float m = s[0][k];
#pragma unroll
            for (int c = 1; c < 9; ++c) m = fmaxf(m, s[c][k]);
            float num = 0.f, den = 0.f;
#pragma unroll
            for (int c = 0; c < 9; ++c) {
                float e = __expf(s[c][k] - m);
                num = fmaf(e, p[c], num);
                den += e;
            }
            ov[k] = 4.f * __fdividef(num, den);
        }

        __builtin_nontemporal_store(ov, reinterpret_cast<vf4*>(
            out + ((size_t)b * FH + y) * FW + (size_t)(cw0 + qx) * 4));
    }
}

extern "C" void kernel_launch(void* const* d_in, const int* in_sizes, int n_in,
                              void* d_out, int out_size, void* d_ws, size_t ws_size,
                              hipStream_t stream) {
    const float* cost = (const float*)d_in[0];
    const float* spg  = (const float*)d_in[1];
    float* outp = (float*)d_out;

    int blocks = 4 * 16 * BB;   // 512
    fused_disp_kernel<<<blocks, 256, 0, stream>>>(cost, spg, outp);
}

// Round 5
// 220.911 us; speedup vs baseline: 1.1287x; 1.1287x over previous
//
#include <hip/hip_runtime.h>
#include <math.h>

// Problem constants: cost [8,1,48,128,240] f32, spg [8,9,512,960] f32
#define BB 8
#define DD 48
#define HH 128
#define WW 240
#define HW (HH * WW)
#define FH (4 * HH)   // 512
#define FW (4 * WW)   // 960
#define FHW (FH * FW)

// clang-native vector types (HIP float2/float4 are classes -> rejected by
// __builtin_nontemporal_*)
typedef float vf2 __attribute__((ext_vector_type(2)));
typedef float vf4 __attribute__((ext_vector_type(4)));

// Stage 1: top-2 along D + softmax-of-2 weighted index -> disp4 [b,h,w]
// One thread per 2 consecutive w pixels (float2 loads), 480 blocks.
__global__ __launch_bounds__(256) void disp4_kernel(const float* __restrict__ cost,
                                                    float* __restrict__ disp4) {
    int t = blockIdx.x * blockDim.x + threadIdx.x;
    const int WQ = WW / 2;                 // 120
    if (t >= BB * HH * WQ) return;
    int wq = t % WQ;
    int r  = t / WQ;
    int hy = r % HH;
    int b  = r / HH;

    const float* base = cost + (size_t)b * DD * HW + (size_t)hy * WW + wq * 2;

    float m1[2], m2[2], i1[2], i2[2];
#pragma unroll
    for (int k = 0; k < 2; ++k) { m1[k] = -INFINITY; m2[k] = -INFINITY; i1[k] = 0.f; i2[k] = 0.f; }

#pragma unroll
    for (int dd = 0; dd < DD; dd += 8) {
        vf2 v[8];
#pragma unroll
        for (int u = 0; u < 8; ++u)
            v[u] = __builtin_nontemporal_load(
                reinterpret_cast<const vf2*>(base + (size_t)(dd + u) * HW));
#pragma unroll
        for (int u = 0; u < 8; ++u) {
            float fd = (float)(dd + u);
            float vv[2] = {v[u].x, v[u].y};
#pragma unroll
            for (int k = 0; k < 2; ++k) {
                // strict > keeps lower index on ties (matches jax.lax.top_k)
                bool g1 = vv[k] > m1[k];
                bool g2 = vv[k] > m2[k];
                m2[k] = g1 ? m1[k] : (g2 ? vv[k] : m2[k]);
                i2[k] = g1 ? i1[k] : (g2 ? fd    : i2[k]);
                m1[k] = g1 ? vv[k] : m1[k];
                i1[k] = g1 ? fd    : i1[k];
            }
        }
    }

    vf2 o;
#pragma unroll
    for (int k = 0; k < 2; ++k) {
        float e = __expf(m2[k] - m1[k]);   // e <= 1 since m1 >= m2
        float s = e / (1.f + e);
        o[k] = i1[k] + (i2[k] - i1[k]) * s;
    }
    *reinterpret_cast<vf2*>(disp4 + (size_t)b * HW + (size_t)hy * WW + wq * 2) = o;
}

// Stage 2: one thread per COARSE pixel -> 16 fine pixels (4 rows x 4 cols).
// The 3x3 disp4 patch is loaded once and reused for all 16 outputs.
// Consecutive threads = consecutive coarse x -> spg/out accesses are
// contiguous 16B/lane (1KB per wave per instruction).
__global__ __launch_bounds__(256) void upfeat_kernel(const float* __restrict__ spg,
                                                     const float* __restrict__ disp4,
                                                     float* __restrict__ out) {
    int t = blockIdx.x * blockDim.x + threadIdx.x;
    if (t >= BB * HH * WW) return;         // 245760
    int cx = t % WW;
    int r  = t / WW;
    int hy = r % HH;
    int b  = r / HH;

    // 3x3 patch of disp4, zero-padded — loaded ONCE per 16 outputs
    float p[9];
#pragma unroll
    for (int i = 0; i < 3; ++i) {
#pragma unroll
        for (int j = 0; j < 3; ++j) {
            int cy = hy + i - 1;
            int cw = cx + j - 1;
            bool ok = (cy >= 0) & (cy < HH) & (cw >= 0) & (cw < WW);
            p[i * 3 + j] = ok ? disp4[(size_t)b * HW + (size_t)cy * WW + cw] : 0.f;
        }
    }

    const float* spb = spg + (size_t)b * 9 * FHW + (size_t)cx * 4;
    float* ob = out + (size_t)b * FHW + (size_t)cx * 4;

#pragma unroll
    for (int dy = 0; dy < 4; ++dy) {
        int y = hy * 4 + dy;
        const float* sp = spb + (size_t)y * FW;

        float s[9][4];
#pragma unroll
        for (int c = 0; c < 9; ++c) {
            vf4 v = __builtin_nontemporal_load(
                reinterpret_cast<const vf4*>(sp + (size_t)c * FHW));
            s[c][0] = v.x; s[c][1] = v.y; s[c][2] = v.z; s[c][3] = v.w;
        }

        vf4 ov;
#pragma unroll
        for (int k = 0; k < 4; ++k) {
            float m = s[0][k];
#pragma unroll
            for (int c = 1; c < 9; ++c) m = fmaxf(m, s[c][k]);
            float num = 0.f, den = 0.f;
#pragma unroll
            for (int c = 0; c < 9; ++c) {
                float e = __expf(s[c][k] - m);
                num = fmaf(e, p[c], num);
                den += e;
            }
            ov[k] = 4.f * __fdividef(num, den);
        }

        __builtin_nontemporal_store(ov, reinterpret_cast<vf4*>(ob + (size_t)y * FW));
    }
}

extern "C" void kernel_launch(void* const* d_in, const int* in_sizes, int n_in,
                              void* d_out, int out_size, void* d_ws, size_t ws_size,
                              hipStream_t stream) {
    const float* cost = (const float*)d_in[0];
    const float* spg  = (const float*)d_in[1];
    float* outp  = (float*)d_out;
    float* disp4 = (float*)d_ws;           // needs BB*HH*WW*4 = 3.93 MB

    {
        int total = BB * HH * (WW / 2);    // 122880
        int blocks = (total + 255) / 256;  // 480
        disp4_kernel<<<blocks, 256, 0, stream>>>(cost, disp4);
    }
    {
        int total = BB * HH * WW;          // 245760
        int blocks = (total + 255) / 256;  // 960
        upfeat_kernel<<<blocks, 256, 0, stream>>>(spg, disp4, outp);
    }
}

// Round 6
// 220.651 us; speedup vs baseline: 1.1300x; 1.0012x over previous
//
#include <hip/hip_runtime.h>
#include <math.h>

// Problem constants: cost [8,1,48,128,240] f32, spg [8,9,512,960] f32
#define BB 8
#define DD 48
#define HH 128
#define WW 240
#define HW (HH * WW)     // 30720 (= 120 * 256)
#define FH (4 * HH)      // 512
#define FW (4 * WW)      // 960
#define FHW (FH * FW)

typedef float vf4 __attribute__((ext_vector_type(4)));

// XCD-aware mapping: block->XCD is round-robin (blk % 8) and BB == 8, so
// b = blk & 7 pins each batch to one XCD. disp4 slice (0.49 MB/batch) then
// stays resident in that XCD's L2 between stage 1 (producer) and stage 2
// (consumer), and patch-row reuse across adjacent row-blocks is L2-local.

// Stage 1: top-2 along D + softmax-of-2 weighted index -> disp4 [b,h,w]
// One thread per coarse pixel; 960 blocks; 8-deep pipelined NT loads.
__global__ __launch_bounds__(256) void disp4_kernel(const float* __restrict__ cost,
                                                    float* __restrict__ disp4) {
    int blk = blockIdx.x;
    int b   = blk & 7;                      // batch == XCD
    int seg = blk >> 3;                     // 0..119
    int p   = seg * 256 + threadIdx.x;      // coarse pixel within batch image

    const float* base = cost + (size_t)b * DD * HW + p;

    float m1 = -INFINITY, m2 = -INFINITY, i1 = 0.f, i2 = 0.f;
#pragma unroll
    for (int dd = 0; dd < DD; dd += 8) {
        float v[8];
#pragma unroll
        for (int u = 0; u < 8; ++u)
            v[u] = __builtin_nontemporal_load(base + (size_t)(dd + u) * HW);
#pragma unroll
        for (int u = 0; u < 8; ++u) {
            float fd = (float)(dd + u);
            // strict > keeps lower index on ties (matches jax.lax.top_k)
            bool g1 = v[u] > m1;
            bool g2 = v[u] > m2;
            m2 = g1 ? m1 : (g2 ? v[u] : m2);
            i2 = g1 ? i1 : (g2 ? fd   : i2);
            m1 = g1 ? v[u] : m1;
            i1 = g1 ? fd   : i1;
        }
    }

    float e = __expf(m2 - m1);              // e <= 1 since m1 >= m2
    float s = e / (1.f + e);
    disp4[(size_t)b * HW + p] = i1 + (i2 - i1) * s;   // regular store -> L2
}

// Stage 2: one thread per coarse pixel -> 16 fine pixels (4 rows x 4 cols).
// 3x3 disp4 patch loaded once (L2-local by XCD pinning); spg NT float4.
__global__ __launch_bounds__(256) void upfeat_kernel(const float* __restrict__ spg,
                                                     const float* __restrict__ disp4,
                                                     float* __restrict__ out) {
    int blk = blockIdx.x;
    int b   = blk & 7;                      // batch == XCD (matches stage 1)
    int seg = blk >> 3;                     // 0..119
    int p   = seg * 256 + threadIdx.x;
    int cx  = p % WW;
    int hy  = p / WW;

    // 3x3 patch of disp4, zero-padded
    float pt[9];
#pragma unroll
    for (int i = 0; i < 3; ++i) {
#pragma unroll
        for (int j = 0; j < 3; ++j) {
            int cy = hy + i - 1;
            int cw = cx + j - 1;
            bool ok = (cy >= 0) & (cy < HH) & (cw >= 0) & (cw < WW);
            pt[i * 3 + j] = ok ? disp4[(size_t)b * HW + (size_t)cy * WW + cw] : 0.f;
        }
    }

    const float* spb = spg + (size_t)b * 9 * FHW + (size_t)cx * 4;
    float* ob = out + (size_t)b * FHW + (size_t)cx * 4;

#pragma unroll
    for (int dy = 0; dy < 4; ++dy) {
        int y = hy * 4 + dy;
        const float* sp = spb + (size_t)y * FW;

        float s[9][4];
#pragma unroll
        for (int c = 0; c < 9; ++c) {
            vf4 v = __builtin_nontemporal_load(
                reinterpret_cast<const vf4*>(sp + (size_t)c * FHW));
            s[c][0] = v.x; s[c][1] = v.y; s[c][2] = v.z; s[c][3] = v.w;
        }

        vf4 ov;
#pragma unroll
        for (int k = 0; k < 4; ++k) {
            float m = s[0][k];
#pragma unroll
            for (int c = 1; c < 9; ++c) m = fmaxf(m, s[c][k]);
            float num = 0.f, den = 0.f;
#pragma unroll
            for (int c = 0; c < 9; ++c) {
                float e = __expf(s[c][k] - m);
                num = fmaf(e, pt[c], num);
                den += e;
            }
            ov[k] = 4.f * __fdividef(num, den);
        }

        __builtin_nontemporal_store(ov, reinterpret_cast<vf4*>(ob + (size_t)y * FW));
    }
}

extern "C" void kernel_launch(void* const* d_in, const int* in_sizes, int n_in,
                              void* d_out, int out_size, void* d_ws, size_t ws_size,
                              hipStream_t stream) {
    const float* cost = (const float*)d_in[0];
    const float* spg  = (const float*)d_in[1];
    float* outp  = (float*)d_out;
    float* disp4 = (float*)d_ws;           // needs BB*HH*WW*4 = 3.93 MB

    // HW == 120*256 exactly -> no bounds checks needed
    disp4_kernel<<<BB * (HW / 256), 256, 0, stream>>>(cost, disp4);      // 960 blocks
    upfeat_kernel<<<BB * (HW / 256), 256, 0, stream>>>(spg, disp4, outp); // 960 blocks
}